// Round 4
// baseline (800.489 us; speedup 1.0000x reference)
//
#include <hip/hip_runtime.h>
#include <cstdint>
#include <stddef.h>

typedef short short8 __attribute__((ext_vector_type(8)));
typedef float floatx4 __attribute__((ext_vector_type(4)));
typedef unsigned short ushortx4 __attribute__((ext_vector_type(4)));

#define MFMA16(a, b, c) __builtin_amdgcn_mfma_f32_16x16x32_bf16((a), (b), (c), 0, 0, 0)

static constexpr int Bv = 2, Sv = 1536, Hv = 2048, NHv = 16, DHv = 128;
static constexpr int Mv = Bv * Sv;  // 3072
static constexpr float SCALE = 0.08838834764831845f;  // 1/sqrt(128), folded into Wq

// fp32 -> bf16 round-to-nearest-even
__device__ inline unsigned short f2bf(float f) {
  union { float f; unsigned u; } c; c.f = f;
  unsigned u = c.u;
  u += 0x7fffu + ((u >> 16) & 1u);
  return (unsigned short)(u >> 16);
}

// async global->LDS, 16B/lane; LDS dest must be wave-uniform (HW adds lane*16)
__device__ inline void async_copy16(const void* g, void* l) {
  auto gp = reinterpret_cast<__attribute__((address_space(1))) uint32_t*>(
      reinterpret_cast<uintptr_t>(g));
  auto lp = reinterpret_cast<__attribute__((address_space(3))) uint32_t*>(
      reinterpret_cast<uintptr_t>(l));
  __builtin_amdgcn_global_load_lds(gp, lp, 16, 0, 0);
}

// merged fp32->bf16 conversion for x + 4 weights (Wq pre-scaled by 1/sqrt(DH))
__global__ void cvt_all_kernel(const float* __restrict__ x,
    const float* __restrict__ Wq, const float* __restrict__ Wk,
    const float* __restrict__ Wv, const float* __restrict__ Wo,
    unsigned short* __restrict__ xb, unsigned short* __restrict__ wqb,
    unsigned short* __restrict__ wkb, unsigned short* __restrict__ wvb,
    unsigned short* __restrict__ wob) {
  const int i = blockIdx.x * 256 + threadIdx.x;
  const int nx4 = (Mv * Hv) / 4;
  const float* src; unsigned short* dst; int j; float scl = 1.0f;
  if (i < nx4) {
    src = x; dst = xb; j = i;
  } else {
    const int i2 = i - nx4;
    const int wsel = i2 >> 20;          // Hv*Hv/4 = 1<<20
    j = i2 & ((1 << 20) - 1);
    if (wsel == 0)      { src = Wq; dst = wqb; scl = SCALE; }
    else if (wsel == 1) { src = Wk; dst = wkb; }
    else if (wsel == 2) { src = Wv; dst = wvb; }
    else                { src = Wo; dst = wob; }
  }
  const float4 v = reinterpret_cast<const float4*>(src)[j];
  ushortx4 o;
  o[0] = f2bf(v.x * scl); o[1] = f2bf(v.y * scl);
  o[2] = f2bf(v.z * scl); o[3] = f2bf(v.w * scl);
  reinterpret_cast<ushortx4*>(dst)[j] = o;
}

// C = A @ W^T. A: Mx2048 bf16 rm, W: 2048x2048 bf16 rm. TM x 128 tiles, BK=64.
// 4 waves in 2x2; XOR source-swizzled async staging; z selects W/C.
// VT: for z==2 write C transposed into Vt layout [b,h,d,tok] (bf16) instead.
template <int TM, bool WF32, bool VT>
__global__ __launch_bounds__(256) void gemm_bt_kernel(
    const unsigned short* __restrict__ A,
    const unsigned short* __restrict__ W0, const unsigned short* __restrict__ W1,
    const unsigned short* __restrict__ W2,
    void* __restrict__ C0, void* __restrict__ C1, void* __restrict__ C2) {
  constexpr int MI = TM / 32;  // M-frags per wave (4 or 2)
  __shared__ __align__(16) unsigned short As[TM * 64];
  __shared__ __align__(16) unsigned short Bs[128 * 64];
  const int z = blockIdx.z;
  const unsigned short* W = (z == 0) ? W0 : ((z == 1) ? W1 : W2);
  const int tid = threadIdx.x;
  const int w = tid >> 6, lane = tid & 63;
  const int quad = lane >> 4, l15 = lane & 15;
  const int wr = w >> 1, wc = w & 1;
  const int tileM = blockIdx.y * TM, tileN = blockIdx.x * 128;

  floatx4 acc[MI][4];
#pragma unroll
  for (int i = 0; i < MI; ++i)
#pragma unroll
    for (int j = 0; j < 4; ++j)
#pragma unroll
      for (int r = 0; r < 4; ++r) acc[i][j][r] = 0.0f;

  // staging descriptors: slot = m*256+tid; row = slot>>3; blk = slot&7 (8x16B per row)
  size_t aoff[MI]; int alb[MI];
#pragma unroll
  for (int m = 0; m < MI; ++m) {
    const int slot = m * 256 + tid;
    const int row = slot >> 3, blk = slot & 7;
    aoff[m] = (size_t)(tileM + row) * 2048 + ((blk ^ (row & 7)) * 8);
    alb[m] = (m * 256 + w * 64) * 8;  // wave-uniform
  }
  size_t boff[4]; int blb[4];
#pragma unroll
  for (int m = 0; m < 4; ++m) {
    const int slot = m * 256 + tid;
    const int row = slot >> 3, blk = slot & 7;
    boff[m] = (size_t)(tileN + row) * 2048 + ((blk ^ (row & 7)) * 8);
    blb[m] = (m * 256 + w * 64) * 8;
  }

  for (int k0 = 0; k0 < 2048; k0 += 64) {
    __syncthreads();
#pragma unroll
    for (int m = 0; m < MI; ++m) async_copy16(A + aoff[m] + k0, As + alb[m]);
#pragma unroll
    for (int m = 0; m < 4; ++m) async_copy16(W + boff[m] + k0, Bs + blb[m]);
    __syncthreads();
#pragma unroll
    for (int kk = 0; kk < 2; ++kk) {
      const int swz = (((kk * 4 + quad) ^ (l15 & 7)) * 8);
      short8 af[MI], bfr[4];
#pragma unroll
      for (int i = 0; i < MI; ++i)
        af[i] = *(const short8*)(As + (wr * (TM / 2) + i * 16 + l15) * 64 + swz);
#pragma unroll
      for (int j = 0; j < 4; ++j)
        bfr[j] = *(const short8*)(Bs + (wc * 64 + j * 16 + l15) * 64 + swz);
#pragma unroll
      for (int i = 0; i < MI; ++i)
#pragma unroll
        for (int j = 0; j < 4; ++j) acc[i][j] = MFMA16(af[i], bfr[j], acc[i][j]);
    }
  }

  if (VT && z == 2) {
    // V^T epilogue: Vt[((b*NH + h)*128 + d)*1536 + tok], 4 consecutive tokens/store
    unsigned short* Vt = (unsigned short*)C2;
    const int bb = (tileM >= Sv) ? 1 : 0;
    const int tokb = tileM - bb * Sv;
    const int hh = blockIdx.x;
    const size_t hbase = (size_t)(bb * NHv + hh) * DHv;
#pragma unroll
    for (int i = 0; i < MI; ++i) {
      const int tok = tokb + wr * (TM / 2) + i * 16 + quad * 4;
#pragma unroll
      for (int j = 0; j < 4; ++j) {
        const int d = wc * 64 + j * 16 + l15;
        ushortx4 pk;
#pragma unroll
        for (int r = 0; r < 4; ++r) pk[r] = f2bf(acc[i][j][r]);
        *(ushortx4*)(Vt + (hbase + d) * Sv + tok) = pk;
      }
    }
    return;
  }

  void* C = (z == 0) ? C0 : ((z == 1) ? C1 : C2);
#pragma unroll
  for (int i = 0; i < MI; ++i) {
#pragma unroll
    for (int r = 0; r < 4; ++r) {
      const int row = tileM + wr * (TM / 2) + i * 16 + quad * 4 + r;
#pragma unroll
      for (int j = 0; j < 4; ++j) {
        const int col = tileN + wc * 64 + j * 16 + l15;
        if (WF32)
          ((float*)C)[(size_t)row * 2048 + col] = acc[i][j][r];
        else
          ((unsigned short*)C)[(size_t)row * 2048 + col] = f2bf(acc[i][j][r]);
      }
    }
  }
}

// Flash attention, bias + causal, no-max softmax (logits bounded; fp32-safe).
// BARRIER-FREE: each wave owns 16 Q rows; K/V MFMA fragments loaded directly
// from global (L1 serves the 4x intra-block reuse); P round-trips through
// per-wave private LDS (lgkmcnt only). Bias double-buffered in registers.
__global__ __launch_bounds__(256, 3) void attn_kernel(
    const unsigned short* __restrict__ Qg, const unsigned short* __restrict__ Kg,
    const unsigned short* __restrict__ Vtg, const float* __restrict__ bias,
    unsigned short* __restrict__ Og) {
  __shared__ __align__(16) unsigned short Ps[4 * 16 * 64];  // per-wave 2KB, swizzled

  const int xb = blockIdx.x;
  const int qt = (xb & 1) ? (23 - (xb >> 1)) : (xb >> 1);  // pairs sum to 25 tiles
  const int h = blockIdx.y, b = blockIdx.z;
  const int tid = threadIdx.x;
  const int w = tid >> 6, lane = tid & 63;
  const int quad = lane >> 4, l15 = lane & 15;
  const int q0 = qt * 64 + w * 16;  // this wave's first Q row

  const size_t bh_base = (size_t)(b * Sv) * Hv + (size_t)h * DHv;
  const size_t vt_base = (size_t)(b * NHv + h) * DHv * Sv;
  const float* biasbase = bias + (size_t)(b * NHv + h) * Sv * Sv;
  unsigned short* pw = Ps + w * 1024;

  // Q frags (A-operand): m = l15, k = kk*32 + quad*8 + jj
  short8 qf[4];
  {
    const unsigned short* qbase = Qg + bh_base + (size_t)(q0 + l15) * Hv;
#pragma unroll
    for (int kk = 0; kk < 4; ++kk)
      qf[kk] = *(const short8*)(qbase + kk * 32 + quad * 8);
  }

  floatx4 o[8];
#pragma unroll
  for (int n = 0; n < 8; ++n)
#pragma unroll
    for (int r = 0; r < 4; ++r) o[n][r] = 0.0f;
  float lrow[4] = {0.0f, 0.0f, 0.0f, 0.0f};

  // bias tile 0 preload
  float bv[4][4];
#pragma unroll
  for (int r = 0; r < 4; ++r) {
    const size_t brow = (size_t)(q0 + quad * 4 + r) * Sv;
#pragma unroll
    for (int j = 0; j < 4; ++j) bv[r][j] = biasbase[brow + j * 16 + l15];
  }

  const unsigned short* kbase = Kg + bh_base;

  for (int kt = 0; kt <= qt; ++kt) {
    const int k0 = kt * 64;

    // K B-frags direct from global: key = k0 + j*16 + l15, dh = kk*32 + quad*8
    short8 kf[4][4];
#pragma unroll
    for (int j = 0; j < 4; ++j) {
      const unsigned short* kr = kbase + (size_t)(k0 + j * 16 + l15) * Hv + quad * 8;
#pragma unroll
      for (int kk = 0; kk < 4; ++kk)
        kf[j][kk] = *(const short8*)(kr + kk * 32);
    }

    // next bias tile prefetch (issued early, consumed next iteration)
    const int kn = (kt < qt) ? k0 + 64 : k0;
    float bvn[4][4];
#pragma unroll
    for (int r = 0; r < 4; ++r) {
      const size_t brow = (size_t)(q0 + quad * 4 + r) * Sv;
#pragma unroll
      for (int j = 0; j < 4; ++j) bvn[r][j] = biasbase[brow + kn + j * 16 + l15];
    }

    // S = Q K^T
    floatx4 sacc[4];
#pragma unroll
    for (int j = 0; j < 4; ++j) {
#pragma unroll
      for (int r = 0; r < 4; ++r) sacc[j][r] = 0.0f;
#pragma unroll
      for (int kk = 0; kk < 4; ++kk)
        sacc[j] = MFMA16(qf[kk], kf[j][kk], sacc[j]);
    }

    // p = exp(s + bias), causal zero on diagonal tile; P -> LDS (swizzled)
    const bool diag = (kt == qt);
#pragma unroll
    for (int r = 0; r < 4; ++r) {
      const int qrow = q0 + quad * 4 + r;
      const int prow = quad * 4 + r;
      float acc_l = 0.0f;
#pragma unroll
      for (int j = 0; j < 4; ++j) {
        const int col = j * 16 + l15;
        float p = __expf(sacc[j][r] + bv[r][j]);
        if (diag && (k0 + col) > qrow) p = 0.0f;
        acc_l += p;
        pw[prow * 64 + ((col >> 3) ^ (prow & 7)) * 8 + (col & 7)] = f2bf(p);
      }
      lrow[r] += acc_l;
    }
#pragma unroll
    for (int r = 0; r < 4; ++r)
#pragma unroll
      for (int j = 0; j < 4; ++j) bv[r][j] = bvn[r][j];

    // O += P @ V ; V B-frags direct from global Vt: dh = n*16+l15, key contiguous
#pragma unroll
    for (int kk = 0; kk < 2; ++kk) {
      const int g = kk * 4 + quad;
      short8 pa = *(const short8*)(pw + l15 * 64 + (g ^ (l15 & 7)) * 8);
      const unsigned short* vr = Vtg + vt_base + (size_t)l15 * Sv + k0 + kk * 32 + quad * 8;
#pragma unroll
      for (int n = 0; n < 8; ++n) {
        short8 vf = *(const short8*)(vr + (size_t)n * 16 * Sv);
        o[n] = MFMA16(pa, vf, o[n]);
      }
    }
  }

  // epilogue: reduce l across the 16 lanes holding each row, normalize, store
#pragma unroll
  for (int r = 0; r < 4; ++r) {
    float ls = lrow[r];
#pragma unroll
    for (int off = 1; off < 16; off <<= 1) ls += __shfl_xor(ls, off, 64);
    const float inv = 1.0f / ls;
    const size_t rowbase = bh_base + (size_t)(q0 + quad * 4 + r) * Hv;
#pragma unroll
    for (int n = 0; n < 8; ++n)
      Og[rowbase + n * 16 + l15] = f2bf(o[n][r] * inv);
  }
}

extern "C" void kernel_launch(void* const* d_in, const int* in_sizes, int n_in,
                              void* d_out, int out_size, void* d_ws, size_t ws_size,
                              hipStream_t stream) {
  const float* x = (const float*)d_in[0];
  const float* bias = (const float*)d_in[1];
  const float* Wq = (const float*)d_in[2];
  const float* Wk = (const float*)d_in[3];
  const float* Wv = (const float*)d_in[4];
  const float* Wo = (const float*)d_in[5];
  float* out = (float*)d_out;

  unsigned short* xb = (unsigned short*)d_ws;
  unsigned short* wqb = xb + (size_t)Mv * Hv;
  unsigned short* wkb = wqb + (size_t)Hv * Hv;
  unsigned short* wvb = wkb + (size_t)Hv * Hv;
  unsigned short* wob = wvb + (size_t)Hv * Hv;
  unsigned short* qb = wob + (size_t)Hv * Hv;
  unsigned short* kb = qb + (size_t)Mv * Hv;
  unsigned short* vtb = kb + (size_t)Mv * Hv;   // V^T written directly by GEMM z==2
  unsigned short* ob = vtb + (size_t)Mv * Hv;
  const size_t needed = ((size_t)Mv * Hv * 5 + (size_t)Hv * Hv * 4) * 2;
  if (ws_size < needed) return;

  const int cvt_n = (Mv * Hv) / 4 + Hv * Hv;
  cvt_all_kernel<<<dim3(cvt_n / 256), 256, 0, stream>>>(
      x, Wq, Wk, Wv, Wo, xb, wqb, wkb, wvb, wob);

  // Q,K = x @ W^T (bf16 rm); V = x @ Wv^T written transposed to Vt layout
  gemm_bt_kernel<128, false, true><<<dim3(16, 24, 3), 256, 0, stream>>>(
      xb, wqb, wkb, wvb, qb, kb, vtb);

  attn_kernel<<<dim3(24, NHv, Bv), 256, 0, stream>>>(qb, kb, vtb, bias, ob);

  // out = attn @ Wo^T (fp32), 64x128 tiles -> 768 blocks
  gemm_bt_kernel<64, true, false><<<dim3(16, 48, 1), 256, 0, stream>>>(
      ob, wob, wob, wob, out, out, out);
}